// Round 5
// baseline (1008.040 us; speedup 1.0000x reference)
//
#include <hip/hip_runtime.h>

#define K_CB   8192
#define D_DIM  256
#define N_ROWS 32768
#define Q_ELEMS (N_ROWS * D_DIM)

#define M_FLAG 1.3e-4f   // np-window 6.1e-5 + bf16 noise + 13-bit pack perturbation (1.5e-5)
#define M_CAND 1.3e-4f
#define CAP    32

typedef __bf16 bf16x8 __attribute__((ext_vector_type(8)));
typedef float  f32x16 __attribute__((ext_vector_type(16)));

// ws layout (bytes):
//   0        Wsq     [8192 f32]
//   32768    Xsq     [32768 f32]
//   163840   rowmin  [32768 f32]  (packed b1: low 13 bits = k)
//   294912   accum f32 | 294916 flag_count u32  (memset 8B)
//   294920   flags   [32768 i32]
//   425992   candcnt [32768 i32]
//   557064   cands   [32768*32 i32]
//   4751376  Wbf     [8192*256 ushort] = bf16(-2w), row-major  (16B aligned)

__device__ inline ushort f2bf(float f) {          // RNE float->bf16
    unsigned u = __float_as_uint(f);
    unsigned r = u + 0x7FFFu + ((u >> 16) & 1u);
    return (ushort)(r >> 16);
}

__device__ inline uint4 pack8(float4 a, float4 b) {
    uint4 o;
    o.x = (unsigned)f2bf(a.x) | ((unsigned)f2bf(a.y) << 16);
    o.y = (unsigned)f2bf(a.z) | ((unsigned)f2bf(a.w) << 16);
    o.z = (unsigned)f2bf(b.x) | ((unsigned)f2bf(b.y) << 16);
    o.w = (unsigned)f2bf(b.z) | ((unsigned)f2bf(b.w) << 16);
    return o;
}

// fused: np-exact w_sq (fp64 sum -> fp32) + Wbf = bf16(-2w)
__global__ void wsq_wbf_kernel(const float* __restrict__ w, float* __restrict__ wsq,
                               ushort* __restrict__ wbf) {
    int wave = threadIdx.x >> 6, lane = threadIdx.x & 63;
    int row = blockIdx.x * 4 + wave;
    float4 v = reinterpret_cast<const float4*>(w)[(size_t)row * 64 + lane];
    uint2 o;
    o.x = (unsigned)f2bf(-2.0f * v.x) | ((unsigned)f2bf(-2.0f * v.y) << 16);
    o.y = (unsigned)f2bf(-2.0f * v.z) | ((unsigned)f2bf(-2.0f * v.w) << 16);
    reinterpret_cast<uint2*>(wbf)[(size_t)row * 64 + lane] = o;
    double s = (double)v.x * v.x + (double)v.y * v.y + (double)v.z * v.z + (double)v.w * v.w;
    #pragma unroll
    for (int off = 32; off > 0; off >>= 1) s += __shfl_down(s, off, 64);
    if (lane == 0) wsq[row] = (float)s;
}

__global__ void sqx_kernel(const float* __restrict__ m, float* __restrict__ out) {
    int wave = threadIdx.x >> 6, lane = threadIdx.x & 63;
    int row = blockIdx.x * 4 + wave;
    float4 v = reinterpret_cast<const float4*>(m)[(size_t)row * 64 + lane];
    double s = (double)v.x * v.x + (double)v.y * v.y + (double)v.z * v.z + (double)v.w * v.w;
    #pragma unroll
    for (int off = 32; off > 0; off >>= 1) s += __shfl_down(s, off, 64);
    if (lane == 0) out[row] = (float)s;
}

// Pass 1: A-in-regs 32x32x16 MFMA argmin, packed-index min/med3 tracking.
// Block = 64 rows, sweeps all 8192 cols in 64 tiles of 128. 2 blocks/CU.
__global__ __launch_bounds__(256, 2) void pass1_kernel(
        const float* __restrict__ x, const ushort* __restrict__ wbf,
        const float* __restrict__ wsq, float* __restrict__ idx_out,
        float* __restrict__ rowmin, int* __restrict__ flags,
        unsigned* __restrict__ flag_count, int* __restrict__ candcnt) {
    __shared__ __align__(16) ushort wt[128 * 256];   // 64 KB, XOR-swizzled 16B slots

    const int t = threadIdx.x;
    const int lane = t & 63, ln31 = lane & 31, h = lane >> 5;
    const int wv = t >> 6, rs = wv & 1, cs = wv >> 1;
    const int r0 = blockIdx.x * 64;

    // A fragments (this wave's 32 rows) -> registers, bf16
    const int arow = r0 + rs * 32 + ln31;
    const float4* xr = reinterpret_cast<const float4*>(x) + (size_t)arow * 64;
    bf16x8 afr[16];
    #pragma unroll
    for (int kk = 0; kk < 16; ++kk) {
        float4 f0 = xr[kk * 4 + h * 2];
        float4 f1 = xr[kk * 4 + h * 2 + 1];
        afr[kk] = __builtin_bit_cast(bf16x8, pack8(f0, f1));
    }

    float b1[16], b2[16];
    #pragma unroll
    for (int r = 0; r < 16; ++r) { b1[r] = 3.4e38f; b2[r] = 3.4e38f; }

    const int col0 = cs * 64 + ln31;        // j=0 col within tile
    const int col1 = col0 + 32;             // (col1 & 7) == (col0 & 7)
    const int c70  = col0 & 7;

    // prefetch tile 0 into registers
    uint4 g[16];
    #pragma unroll
    for (int i = 0; i < 16; ++i)
        g[i] = reinterpret_cast<const uint4*>(wbf)[i * 256 + t];

    for (int tile = 0; tile < 64; ++tile) {
        __syncthreads();                    // readers of previous tile done
        #pragma unroll
        for (int i = 0; i < 16; ++i) {
            int li = i * 256 + t, c = li >> 5, s = li & 31;
            *reinterpret_cast<uint4*>(&wt[c * 256 + ((s ^ (c & 7)) * 8)]) = g[i];
        }
        __syncthreads();
        if (tile < 63) {
            #pragma unroll
            for (int i = 0; i < 16; ++i)
                g[i] = reinterpret_cast<const uint4*>(wbf)[(size_t)(tile + 1) * 4096 + i * 256 + t];
        }

        int kb = tile * 128 + col0;
        float wsk0 = wsq[kb];
        float wsk1 = wsq[kb + 32];

        f32x16 acc0 = {0,0,0,0,0,0,0,0,0,0,0,0,0,0,0,0};
        f32x16 acc1 = {0,0,0,0,0,0,0,0,0,0,0,0,0,0,0,0};
        #pragma unroll
        for (int kk = 0; kk < 16; ++kk) {
            int s = kk * 2 + h;
            bf16x8 bf0 = *reinterpret_cast<const bf16x8*>(&wt[col0 * 256 + ((s ^ c70) * 8)]);
            bf16x8 bf1 = *reinterpret_cast<const bf16x8*>(&wt[col1 * 256 + ((s ^ c70) * 8)]);
            acc0 = __builtin_amdgcn_mfma_f32_32x32x16_bf16(afr[kk], bf0, acc0, 0, 0, 0);
            acc1 = __builtin_amdgcn_mfma_f32_32x32x16_bf16(afr[kk], bf1, acc1, 0, 0, 0);
        }

        // score = acc + wsq (Wbf carries -2); pack k into low 13 mantissa bits
        #pragma unroll
        for (int r = 0; r < 16; ++r) {
            float s0 = acc0[r] + wsk0;
            float p0 = __uint_as_float((__float_as_uint(s0) & 0xFFFFE000u) | (unsigned)kb);
            b2[r] = __builtin_amdgcn_fmed3f(p0, b1[r], b2[r]);
            b1[r] = fminf(p0, b1[r]);
            float s1 = acc1[r] + wsk1;
            float p1 = __uint_as_float((__float_as_uint(s1) & 0xFFFFE000u) | (unsigned)(kb + 32));
            b2[r] = __builtin_amdgcn_fmed3f(p1, b1[r], b2[r]);
            b1[r] = fminf(p1, b1[r]);
        }
    }

    // cross-lane reduction via LDS (reuse wt)
    __syncthreads();
    float* sb1 = reinterpret_cast<float*>(wt);
    float* sb2 = sb1 + 4096;
    #pragma unroll
    for (int r = 0; r < 16; ++r) {
        int rl = rs * 32 + (r & 3) + 8 * (r >> 2) + 4 * h;
        sb1[rl * 64 + cs * 32 + ln31] = b1[r];
        sb2[rl * 64 + cs * 32 + ln31] = b2[r];
    }
    __syncthreads();
    if (t < 64) {
        float B1 = 3.4e38f, B2 = 3.4e38f;
        for (int c = 0; c < 64; ++c) {
            float a1 = sb1[t * 64 + c], a2 = sb2[t * 64 + c];
            float nb2 = fminf(fmaxf(B1, a1), fminf(B2, a2));  // 2nd-smallest of {B1,B2,a1,a2}
            B1 = fminf(B1, a1);
            B2 = nb2;
        }
        int row = r0 + t;
        idx_out[row] = (float)(__float_as_uint(B1) & 0x1FFFu);
        rowmin[row]  = B1;
        candcnt[row] = 0;
        if (B2 - B1 <= M_FLAG) {
            unsigned pos = atomicAdd(flag_count, 1u);
            if (pos < N_ROWS) flags[pos] = row;
        }
    }
}

// Fixup: same MFMA structure over gathered flagged rows, k-split 8 for parallelism.
// Appends candidates with score <= rowmin + M_CAND into per-row global lists.
__global__ __launch_bounds__(256, 2) void fixup_kernel(
        const float* __restrict__ x, const ushort* __restrict__ wbf,
        const float* __restrict__ wsq, const float* __restrict__ rowmin,
        const int* __restrict__ flags, const unsigned* __restrict__ flag_count,
        int* __restrict__ candcnt, int* __restrict__ cands) {
    __shared__ __align__(16) ushort wt[128 * 256];
    __shared__ int   sh_rows[64];
    __shared__ float sh_thr[64];

    const int t = threadIdx.x;
    const int lane = t & 63, ln31 = lane & 31, h = lane >> 5;
    const int wv = t >> 6, rs = wv & 1, cs = wv >> 1;

    unsigned cu = flag_count[0];
    int cnt = cu > N_ROWS ? N_ROWS : (int)cu;
    int nunits = ((cnt + 63) >> 6) * 8;

    for (int u = blockIdx.x; u < nunits; u += 512) {
        int ksp  = u & 7;                 // 1024-col slice
        int base = (u >> 3) * 64;
        int nrows = cnt - base; if (nrows > 64) nrows = 64;

        __syncthreads();                  // protect wt/sh from previous unit
        if (t < 64) {
            int valid = (t < nrows);
            int gr = flags[base + (valid ? t : 0)];
            sh_rows[t] = gr;
            sh_thr[t]  = valid ? rowmin[gr] + M_CAND : -3.4e38f;  // invalid: never matches
        }
        __syncthreads();

        int arow = sh_rows[rs * 32 + ln31];
        const float4* xr = reinterpret_cast<const float4*>(x) + (size_t)arow * 64;
        bf16x8 afr[16];
        #pragma unroll
        for (int kk = 0; kk < 16; ++kk) {
            float4 f0 = xr[kk * 4 + h * 2], f1 = xr[kk * 4 + h * 2 + 1];
            afr[kk] = __builtin_bit_cast(bf16x8, pack8(f0, f1));
        }
        float thr_r[16];
        #pragma unroll
        for (int r = 0; r < 16; ++r)
            thr_r[r] = sh_thr[rs * 32 + (r & 3) + 8 * (r >> 2) + 4 * h];

        const int col0 = cs * 64 + ln31, col1 = col0 + 32, c70 = col0 & 7;

        for (int tile = 0; tile < 8; ++tile) {
            int ct0 = ksp * 1024 + tile * 128;
            __syncthreads();
            #pragma unroll
            for (int i = 0; i < 16; ++i) {
                int li = i * 256 + t, c = li >> 5, s = li & 31;
                *reinterpret_cast<uint4*>(&wt[c * 256 + ((s ^ (c & 7)) * 8)]) =
                    reinterpret_cast<const uint4*>(wbf)[(size_t)ct0 * 32 + li];
            }
            __syncthreads();

            float wsk0 = wsq[ct0 + col0], wsk1 = wsq[ct0 + col1];
            f32x16 acc0 = {0,0,0,0,0,0,0,0,0,0,0,0,0,0,0,0};
            f32x16 acc1 = {0,0,0,0,0,0,0,0,0,0,0,0,0,0,0,0};
            #pragma unroll
            for (int kk = 0; kk < 16; ++kk) {
                int s = kk * 2 + h;
                bf16x8 bf0 = *reinterpret_cast<const bf16x8*>(&wt[col0 * 256 + ((s ^ c70) * 8)]);
                bf16x8 bf1 = *reinterpret_cast<const bf16x8*>(&wt[col1 * 256 + ((s ^ c70) * 8)]);
                acc0 = __builtin_amdgcn_mfma_f32_32x32x16_bf16(afr[kk], bf0, acc0, 0, 0, 0);
                acc1 = __builtin_amdgcn_mfma_f32_32x32x16_bf16(afr[kk], bf1, acc1, 0, 0, 0);
            }
            #pragma unroll
            for (int r = 0; r < 16; ++r) {
                int rl = rs * 32 + (r & 3) + 8 * (r >> 2) + 4 * h;
                float s0 = acc0[r] + wsk0;
                if (s0 <= thr_r[r]) {
                    int grow = sh_rows[rl];
                    int pos = atomicAdd(&candcnt[grow], 1);
                    if (pos < CAP) cands[grow * CAP + pos] = ct0 + col0;
                }
                float s1 = acc1[r] + wsk1;
                if (s1 <= thr_r[r]) {
                    int grow = sh_rows[rl];
                    int pos = atomicAdd(&candcnt[grow], 1);
                    if (pos < CAP) cands[grow * CAP + pos] = ct0 + col1;
                }
            }
        }
    }
}

// np-exact rescore (verified R3): q = fl32(fl32(Xsq - 2*fl32(dot64)) + Wsq), lowest-index ties
__global__ __launch_bounds__(256) void rescore_kernel(
        const float* __restrict__ x, const float* __restrict__ w,
        const float* __restrict__ wsq, const float* __restrict__ xsq,
        const int* __restrict__ flags, const unsigned* __restrict__ flag_count,
        const int* __restrict__ candcnt, const int* __restrict__ cands,
        float* __restrict__ idx_out) {
    int wid  = (blockIdx.x * 256 + threadIdx.x) >> 6;
    int lane = threadIdx.x & 63;
    unsigned cu = flag_count[0];
    int cnt = (cu > N_ROWS) ? N_ROWS : (int)cu;

    for (int fi = wid; fi < cnt; fi += 1024) {
        int row = flags[fi];
        float4 xv = reinterpret_cast<const float4*>(x)[(size_t)row * 64 + lane];
        float Xs = xsq[row];
        int nc = candcnt[row]; if (nc > CAP) nc = CAP;
        float bq = 3.4e38f; int bk = -1;
        for (int c = 0; c < nc; ++c) {
            int k = cands[row * CAP + c];
            float4 wv = reinterpret_cast<const float4*>(w)[(size_t)k * 64 + lane];
            double d = (double)xv.x * wv.x + (double)xv.y * wv.y
                     + (double)xv.z * wv.z + (double)xv.w * wv.w;
            #pragma unroll
            for (int off = 1; off < 64; off <<= 1) d += __shfl_xor(d, off, 64);
            float XW = (float)d;
            float t3 = fmaf(-2.0f, XW, Xs);
            float qv = t3 + wsq[k];
            if (qv < bq || (qv == bq && k < bk) || bk < 0) { bq = qv; bk = k; }
        }
        if (lane == 0 && bk >= 0) idx_out[row] = (float)bk;
    }
}

__global__ __launch_bounds__(256) void gather_loss_kernel(
        const float* __restrict__ x, const float* __restrict__ w,
        const float* __restrict__ idx_f, float* __restrict__ out_q,
        float* __restrict__ accum) {
    const int nf4 = Q_ELEMS / 4;
    float lsum = 0.0f;
    for (int e = blockIdx.x * blockDim.x + threadIdx.x; e < nf4;
         e += gridDim.x * blockDim.x) {
        int row = e >> 6, d4 = e & 63;
        int k = (int)idx_f[row];
        float4 xv = reinterpret_cast<const float4*>(x)[e];
        float4 qv = reinterpret_cast<const float4*>(w)[(size_t)k * 64 + d4];
        float4 ov;
        ov.x = xv.x + (qv.x - xv.x);
        ov.y = xv.y + (qv.y - xv.y);
        ov.z = xv.z + (qv.z - xv.z);
        ov.w = xv.w + (qv.w - xv.w);
        reinterpret_cast<float4*>(out_q)[e] = ov;
        float dx = xv.x - qv.x, dy = xv.y - qv.y, dz = xv.z - qv.z, dw = xv.w - qv.w;
        lsum += dx * dx + dy * dy + dz * dz + dw * dw;
    }
    #pragma unroll
    for (int off = 32; off > 0; off >>= 1) lsum += __shfl_down(lsum, off, 64);
    __shared__ float ssum[4];
    if ((threadIdx.x & 63) == 0) ssum[threadIdx.x >> 6] = lsum;
    __syncthreads();
    if (threadIdx.x == 0)
        atomicAdd(accum, ssum[0] + ssum[1] + ssum[2] + ssum[3]);
}

__global__ void finalize_kernel(const float* __restrict__ accum,
                                float* __restrict__ out_tail) {
    float mse = accum[0] / (float)Q_ELEMS;
    float commit = 0.25f * mse;
    out_tail[0] = commit;
    out_tail[1] = mse;
    out_tail[2] = commit + mse;
}

extern "C" void kernel_launch(void* const* d_in, const int* in_sizes, int n_in,
                              void* d_out, int out_size, void* d_ws, size_t ws_size,
                              hipStream_t stream) {
    const float* x = (const float*)d_in[0];
    const float* w = (const float*)d_in[1];
    float* out = (float*)d_out;

    char* ws = (char*)d_ws;
    float*    Wsq        = (float*)ws;
    float*    Xsq        = (float*)(ws + 32768);
    float*    Rmin       = (float*)(ws + 163840);
    float*    accum      = (float*)(ws + 294912);
    unsigned* flag_count = (unsigned*)(ws + 294916);
    int*      flags      = (int*)(ws + 294920);
    int*      candcnt    = (int*)(ws + 425992);
    int*      cands      = (int*)(ws + 557064);
    ushort*   Wbf        = (ushort*)(ws + 4751376);

    hipMemsetAsync(ws + 294912, 0, 8, stream);   // accum + flag_count
    wsq_wbf_kernel<<<K_CB / 4, 256, 0, stream>>>(w, Wsq, Wbf);
    sqx_kernel<<<N_ROWS / 4, 256, 0, stream>>>(x, Xsq);
    pass1_kernel<<<N_ROWS / 64, 256, 0, stream>>>(x, Wbf, Wsq, out + Q_ELEMS,
                                                  Rmin, flags, flag_count, candcnt);
    fixup_kernel<<<512, 256, 0, stream>>>(x, Wbf, Wsq, Rmin, flags, flag_count,
                                          candcnt, cands);
    rescore_kernel<<<256, 256, 0, stream>>>(x, w, Wsq, Xsq, flags, flag_count,
                                            candcnt, cands, out + Q_ELEMS);
    gather_loss_kernel<<<8192, 256, 0, stream>>>(x, w, out + Q_ELEMS, out, accum);
    finalize_kernel<<<1, 1, 0, stream>>>(accum, out + Q_ELEMS + N_ROWS);
}

// Round 6
// 449.501 us; speedup vs baseline: 2.2426x; 2.2426x over previous
//
#include <hip/hip_runtime.h>

#define K_CB   8192
#define D_DIM  256
#define N_ROWS 32768
#define Q_ELEMS (N_ROWS * D_DIM)

#define M_FLAG 1.3e-4f   // np-window 6.1e-5 + bf16 score noise (sigma~2e-6) + 13-bit pack (1.5e-5)
#define M_CAND 1.3e-4f
#define CAP    32

typedef __bf16 bf16x8 __attribute__((ext_vector_type(8)));
typedef float  f32x16 __attribute__((ext_vector_type(16)));

// async 16B global->LDS DMA: LDS dest is WAVE-UNIFORM base; HW adds lane*16.
#define ASYNC_COPY16(gp, lp)                                              \
    __builtin_amdgcn_global_load_lds(                                     \
        (const __attribute__((address_space(1))) unsigned int*)(gp),      \
        (__attribute__((address_space(3))) unsigned int*)(lp), 16, 0, 0)

// ws layout (bytes):
//   0        Wsq     [8192 f32]
//   32768    Xsq     [32768 f32]
//   163840   rowmin  [32768 f32]  (packed b1: low 13 bits = k)
//   294912   accum f32 | 294916 flag_count u32  (memset 8B)
//   294920   flags   [32768 i32]
//   425992   candcnt [32768 i32]
//   557064   cands   [32768*32 i32]
//   4751376  Wbf     [8192*256 ushort] = bf16(-2w), PRE-SWIZZLED tile layout:
//            byte(k,s) = (k>>7)*65536 + (k&127)*512 + ((s ^ ((k&127)&7))*16), s = 16B dim-chunk

__device__ inline ushort f2bf(float f) {          // RNE float->bf16
    unsigned u = __float_as_uint(f);
    unsigned r = u + 0x7FFFu + ((u >> 16) & 1u);
    return (ushort)(r >> 16);
}

__device__ inline uint4 pack8(float4 a, float4 b) {
    uint4 o;
    o.x = (unsigned)f2bf(a.x) | ((unsigned)f2bf(a.y) << 16);
    o.y = (unsigned)f2bf(a.z) | ((unsigned)f2bf(a.w) << 16);
    o.z = (unsigned)f2bf(b.x) | ((unsigned)f2bf(b.y) << 16);
    o.w = (unsigned)f2bf(b.z) | ((unsigned)f2bf(b.w) << 16);
    return o;
}

// fused: np-exact w_sq (fp64 sum -> fp32) + Wbf = bf16(-2w), pre-swizzled
__global__ void wsq_wbf_kernel(const float* __restrict__ w, float* __restrict__ wsq,
                               ushort* __restrict__ wbf) {
    int wave = threadIdx.x >> 6, lane = threadIdx.x & 63;
    int row = blockIdx.x * 4 + wave;                 // codeword k
    float4 v = reinterpret_cast<const float4*>(w)[(size_t)row * 64 + lane];
    uint2 o;
    o.x = (unsigned)f2bf(-2.0f * v.x) | ((unsigned)f2bf(-2.0f * v.y) << 16);
    o.y = (unsigned)f2bf(-2.0f * v.z) | ((unsigned)f2bf(-2.0f * v.w) << 16);
    int c = row & 127, tile = row >> 7;
    int s = lane >> 1, hq = lane & 1;                // lane covers dims [lane*4,+4)
    size_t dst = (size_t)tile * 65536 + (size_t)c * 512 + (size_t)((s ^ (c & 7)) * 16) + hq * 8;
    *reinterpret_cast<uint2*>((char*)wbf + dst) = o;
    double sq = (double)v.x * v.x + (double)v.y * v.y + (double)v.z * v.z + (double)v.w * v.w;
    #pragma unroll
    for (int off = 32; off > 0; off >>= 1) sq += __shfl_down(sq, off, 64);
    if (lane == 0) wsq[row] = (float)sq;
}

__global__ void sqx_kernel(const float* __restrict__ m, float* __restrict__ out) {
    int wave = threadIdx.x >> 6, lane = threadIdx.x & 63;
    int row = blockIdx.x * 4 + wave;
    float4 v = reinterpret_cast<const float4*>(m)[(size_t)row * 64 + lane];
    double s = (double)v.x * v.x + (double)v.y * v.y + (double)v.z * v.z + (double)v.w * v.w;
    #pragma unroll
    for (int off = 32; off > 0; off >>= 1) s += __shfl_down(s, off, 64);
    if (lane == 0) out[row] = (float)s;
}

// Pass 1: A-in-regs 32x32x16 MFMA argmin; W staged via global_load_lds DMA.
__global__ __launch_bounds__(256, 2) void pass1_kernel(
        const float* __restrict__ x, const ushort* __restrict__ wbf,
        const float* __restrict__ wsq, float* __restrict__ idx_out,
        float* __restrict__ rowmin, int* __restrict__ flags,
        unsigned* __restrict__ flag_count, int* __restrict__ candcnt) {
    __shared__ __align__(16) ushort wt[128 * 256];   // 64 KB swizzled W tile

    const int t = threadIdx.x;
    const int lane = t & 63, ln31 = lane & 31, h = lane >> 5;
    const int wv = t >> 6, rs = wv & 1, cs = wv >> 1;
    const int r0 = blockIdx.x * 64;

    // A fragments (this wave's 32 rows) -> registers
    const int arow = r0 + rs * 32 + ln31;
    const float4* xr = reinterpret_cast<const float4*>(x) + (size_t)arow * 64;
    bf16x8 afr[16];
    #pragma unroll
    for (int kk = 0; kk < 16; ++kk)
        afr[kk] = __builtin_bit_cast(bf16x8, pack8(xr[kk * 4 + h * 2], xr[kk * 4 + h * 2 + 1]));

    float b1[16], b2[16];
    #pragma unroll
    for (int r = 0; r < 16; ++r) { b1[r] = 3.4e38f; b2[r] = 3.4e38f; }

    const int col0 = cs * 64 + ln31, c70 = col0 & 7;
    const char* gW = (const char*)wbf + (size_t)wv * 16384 + (size_t)lane * 16;  // per-lane global
    char* lW = (char*)wt + wv * 16384;                                           // wave-uniform LDS

    for (int tile = 0; tile < 64; ++tile) {
        __syncthreads();                              // previous tile fully consumed
        const char* gt = gW + (size_t)tile * 65536;
        #pragma unroll
        for (int i = 0; i < 16; ++i)
            ASYNC_COPY16(gt + i * 1024, lW + i * 1024);
        __syncthreads();                              // drains vmcnt before reads

        int kb = tile * 128 + col0;
        float wsk0 = wsq[kb], wsk1 = wsq[kb + 32];

        f32x16 acc0 = {0,0,0,0,0,0,0,0,0,0,0,0,0,0,0,0};
        f32x16 acc1 = {0,0,0,0,0,0,0,0,0,0,0,0,0,0,0,0};
        #pragma unroll
        for (int kk = 0; kk < 16; ++kk) {
            int s = kk * 2 + h;
            bf16x8 bf0 = *reinterpret_cast<const bf16x8*>(&wt[col0 * 256 + ((s ^ c70) * 8)]);
            bf16x8 bf1 = *reinterpret_cast<const bf16x8*>(&wt[(col0 + 32) * 256 + ((s ^ c70) * 8)]);
            acc0 = __builtin_amdgcn_mfma_f32_32x32x16_bf16(afr[kk], bf0, acc0, 0, 0, 0);
            acc1 = __builtin_amdgcn_mfma_f32_32x32x16_bf16(afr[kk], bf1, acc1, 0, 0, 0);
        }

        #pragma unroll
        for (int r = 0; r < 16; ++r) {
            float s0 = acc0[r] + wsk0;
            float p0 = __uint_as_float((__float_as_uint(s0) & 0xFFFFE000u) | (unsigned)kb);
            b2[r] = __builtin_amdgcn_fmed3f(p0, b1[r], b2[r]);
            b1[r] = fminf(p0, b1[r]);
            float s1 = acc1[r] + wsk1;
            float p1 = __uint_as_float((__float_as_uint(s1) & 0xFFFFE000u) | (unsigned)(kb + 32));
            b2[r] = __builtin_amdgcn_fmed3f(p1, b1[r], b2[r]);
            b1[r] = fminf(p1, b1[r]);
        }
    }

    // cross-lane reduction via LDS (reuse wt: 8192 floats = 32 KB)
    __syncthreads();
    float* sb1 = reinterpret_cast<float*>(wt);
    float* sb2 = sb1 + 4096;
    #pragma unroll
    for (int r = 0; r < 16; ++r) {
        int rl = rs * 32 + (r & 3) + 8 * (r >> 2) + 4 * h;   // C/D row mapping (verified R5)
        sb1[rl * 64 + cs * 32 + ln31] = b1[r];
        sb2[rl * 64 + cs * 32 + ln31] = b2[r];
    }
    __syncthreads();
    if (t < 64) {
        float B1 = 3.4e38f, B2 = 3.4e38f;
        for (int c = 0; c < 64; ++c) {
            float a1 = sb1[t * 64 + c], a2 = sb2[t * 64 + c];
            float nb2 = fminf(fmaxf(B1, a1), fminf(B2, a2));  // 2nd-smallest of {B1,B2,a1,a2}
            B1 = fminf(B1, a1);
            B2 = nb2;
        }
        int row = r0 + t;
        idx_out[row] = (float)(__float_as_uint(B1) & 0x1FFFu);
        rowmin[row]  = B1;
        candcnt[row] = 0;
        if (B2 - B1 <= M_FLAG) {
            unsigned pos = atomicAdd(flag_count, 1u);
            if (pos < N_ROWS) flags[pos] = row;
        }
    }
}

// Fixup: same MFMA structure over gathered flagged rows, k-split 8; DMA staging.
__global__ __launch_bounds__(256, 2) void fixup_kernel(
        const float* __restrict__ x, const ushort* __restrict__ wbf,
        const float* __restrict__ wsq, const float* __restrict__ rowmin,
        const int* __restrict__ flags, const unsigned* __restrict__ flag_count,
        int* __restrict__ candcnt, int* __restrict__ cands) {
    __shared__ __align__(16) ushort wt[128 * 256];
    __shared__ int   sh_rows[64];
    __shared__ float sh_thr[64];

    const int t = threadIdx.x;
    const int lane = t & 63, ln31 = lane & 31, h = lane >> 5;
    const int wv = t >> 6, rs = wv & 1, cs = wv >> 1;

    unsigned cu = flag_count[0];
    int cnt = cu > N_ROWS ? N_ROWS : (int)cu;
    int nunits = ((cnt + 63) >> 6) * 8;

    for (int u = blockIdx.x; u < nunits; u += 512) {
        int ksp  = u & 7;                 // 1024-col slice
        int base = (u >> 3) * 64;
        int nrows = cnt - base; if (nrows > 64) nrows = 64;

        __syncthreads();                  // protect wt/sh from previous unit
        if (t < 64) {
            int valid = (t < nrows);
            int gr = flags[base + (valid ? t : 0)];
            sh_rows[t] = gr;
            sh_thr[t]  = valid ? rowmin[gr] + M_CAND : -3.4e38f;
        }
        __syncthreads();

        int arow = sh_rows[rs * 32 + ln31];
        const float4* xr = reinterpret_cast<const float4*>(x) + (size_t)arow * 64;
        bf16x8 afr[16];
        #pragma unroll
        for (int kk = 0; kk < 16; ++kk)
            afr[kk] = __builtin_bit_cast(bf16x8, pack8(xr[kk * 4 + h * 2], xr[kk * 4 + h * 2 + 1]));
        float thr_r[16];
        int   rl_r[16];
        #pragma unroll
        for (int r = 0; r < 16; ++r) {
            rl_r[r]  = rs * 32 + (r & 3) + 8 * (r >> 2) + 4 * h;
            thr_r[r] = sh_thr[rl_r[r]];
        }

        const int col0 = cs * 64 + ln31, c70 = col0 & 7;
        char* lW = (char*)wt + wv * 16384;

        for (int tile = 0; tile < 8; ++tile) {
            int ct0 = ksp * 1024 + tile * 128;
            __syncthreads();
            const char* gt = (const char*)wbf + ((size_t)ct0 << 9)
                           + (size_t)wv * 16384 + (size_t)lane * 16;
            #pragma unroll
            for (int i = 0; i < 16; ++i)
                ASYNC_COPY16(gt + i * 1024, lW + i * 1024);
            __syncthreads();

            float wsk0 = wsq[ct0 + col0], wsk1 = wsq[ct0 + col0 + 32];
            f32x16 acc0 = {0,0,0,0,0,0,0,0,0,0,0,0,0,0,0,0};
            f32x16 acc1 = {0,0,0,0,0,0,0,0,0,0,0,0,0,0,0,0};
            #pragma unroll
            for (int kk = 0; kk < 16; ++kk) {
                int s = kk * 2 + h;
                bf16x8 bf0 = *reinterpret_cast<const bf16x8*>(&wt[col0 * 256 + ((s ^ c70) * 8)]);
                bf16x8 bf1 = *reinterpret_cast<const bf16x8*>(&wt[(col0 + 32) * 256 + ((s ^ c70) * 8)]);
                acc0 = __builtin_amdgcn_mfma_f32_32x32x16_bf16(afr[kk], bf0, acc0, 0, 0, 0);
                acc1 = __builtin_amdgcn_mfma_f32_32x32x16_bf16(afr[kk], bf1, acc1, 0, 0, 0);
            }
            #pragma unroll
            for (int r = 0; r < 16; ++r) {
                float s0 = acc0[r] + wsk0;
                if (s0 <= thr_r[r]) {
                    int grow = sh_rows[rl_r[r]];
                    int pos = atomicAdd(&candcnt[grow], 1);
                    if (pos < CAP) cands[grow * CAP + pos] = ct0 + col0;
                }
                float s1 = acc1[r] + wsk1;
                if (s1 <= thr_r[r]) {
                    int grow = sh_rows[rl_r[r]];
                    int pos = atomicAdd(&candcnt[grow], 1);
                    if (pos < CAP) cands[grow * CAP + pos] = ct0 + col0 + 32;
                }
            }
        }
    }
}

// np-exact rescore (verified R3): q = fl32(fl32(Xsq - 2*fl32(dot64)) + Wsq), lowest-index ties
__global__ __launch_bounds__(256) void rescore_kernel(
        const float* __restrict__ x, const float* __restrict__ w,
        const float* __restrict__ wsq, const float* __restrict__ xsq,
        const int* __restrict__ flags, const unsigned* __restrict__ flag_count,
        const int* __restrict__ candcnt, const int* __restrict__ cands,
        float* __restrict__ idx_out) {
    int wid  = (blockIdx.x * 256 + threadIdx.x) >> 6;
    int lane = threadIdx.x & 63;
    unsigned cu = flag_count[0];
    int cnt = (cu > N_ROWS) ? N_ROWS : (int)cu;

    for (int fi = wid; fi < cnt; fi += 1024) {
        int row = flags[fi];
        float4 xv = reinterpret_cast<const float4*>(x)[(size_t)row * 64 + lane];
        float Xs = xsq[row];
        int nc = candcnt[row]; if (nc > CAP) nc = CAP;
        float bq = 3.4e38f; int bk = -1;
        for (int c = 0; c < nc; ++c) {
            int k = cands[row * CAP + c];
            float4 wv = reinterpret_cast<const float4*>(w)[(size_t)k * 64 + lane];
            double d = (double)xv.x * wv.x + (double)xv.y * wv.y
                     + (double)xv.z * wv.z + (double)xv.w * wv.w;
            #pragma unroll
            for (int off = 1; off < 64; off <<= 1) d += __shfl_xor(d, off, 64);
            float XW = (float)d;
            float t3 = fmaf(-2.0f, XW, Xs);
            float qv = t3 + wsq[k];
            if (qv < bq || (qv == bq && k < bk) || bk < 0) { bq = qv; bk = k; }
        }
        if (lane == 0 && bk >= 0) idx_out[row] = (float)bk;
    }
}

__global__ __launch_bounds__(256) void gather_loss_kernel(
        const float* __restrict__ x, const float* __restrict__ w,
        const float* __restrict__ idx_f, float* __restrict__ out_q,
        float* __restrict__ accum) {
    const int nf4 = Q_ELEMS / 4;
    float lsum = 0.0f;
    for (int e = blockIdx.x * blockDim.x + threadIdx.x; e < nf4;
         e += gridDim.x * blockDim.x) {
        int row = e >> 6, d4 = e & 63;
        int k = (int)idx_f[row];
        float4 xv = reinterpret_cast<const float4*>(x)[e];
        float4 qv = reinterpret_cast<const float4*>(w)[(size_t)k * 64 + d4];
        float4 ov;
        ov.x = xv.x + (qv.x - xv.x);
        ov.y = xv.y + (qv.y - xv.y);
        ov.z = xv.z + (qv.z - xv.z);
        ov.w = xv.w + (qv.w - xv.w);
        reinterpret_cast<float4*>(out_q)[e] = ov;
        float dx = xv.x - qv.x, dy = xv.y - qv.y, dz = xv.z - qv.z, dw = xv.w - qv.w;
        lsum += dx * dx + dy * dy + dz * dz + dw * dw;
    }
    #pragma unroll
    for (int off = 32; off > 0; off >>= 1) lsum += __shfl_down(lsum, off, 64);
    __shared__ float ssum[4];
    if ((threadIdx.x & 63) == 0) ssum[threadIdx.x >> 6] = lsum;
    __syncthreads();
    if (threadIdx.x == 0)
        atomicAdd(accum, ssum[0] + ssum[1] + ssum[2] + ssum[3]);
}

__global__ void finalize_kernel(const float* __restrict__ accum,
                                float* __restrict__ out_tail) {
    float mse = accum[0] / (float)Q_ELEMS;
    float commit = 0.25f * mse;
    out_tail[0] = commit;
    out_tail[1] = mse;
    out_tail[2] = commit + mse;
}

extern "C" void kernel_launch(void* const* d_in, const int* in_sizes, int n_in,
                              void* d_out, int out_size, void* d_ws, size_t ws_size,
                              hipStream_t stream) {
    const float* x = (const float*)d_in[0];
    const float* w = (const float*)d_in[1];
    float* out = (float*)d_out;

    char* ws = (char*)d_ws;
    float*    Wsq        = (float*)ws;
    float*    Xsq        = (float*)(ws + 32768);
    float*    Rmin       = (float*)(ws + 163840);
    float*    accum      = (float*)(ws + 294912);
    unsigned* flag_count = (unsigned*)(ws + 294916);
    int*      flags      = (int*)(ws + 294920);
    int*      candcnt    = (int*)(ws + 425992);
    int*      cands      = (int*)(ws + 557064);
    ushort*   Wbf        = (ushort*)(ws + 4751376);

    hipMemsetAsync(ws + 294912, 0, 8, stream);   // accum + flag_count
    wsq_wbf_kernel<<<K_CB / 4, 256, 0, stream>>>(w, Wsq, Wbf);
    sqx_kernel<<<N_ROWS / 4, 256, 0, stream>>>(x, Xsq);
    pass1_kernel<<<N_ROWS / 64, 256, 0, stream>>>(x, Wbf, Wsq, out + Q_ELEMS,
                                                  Rmin, flags, flag_count, candcnt);
    fixup_kernel<<<512, 256, 0, stream>>>(x, Wbf, Wsq, Rmin, flags, flag_count,
                                          candcnt, cands);
    rescore_kernel<<<256, 256, 0, stream>>>(x, w, Wsq, Xsq, flags, flag_count,
                                            candcnt, cands, out + Q_ELEMS);
    gather_loss_kernel<<<8192, 256, 0, stream>>>(x, w, out + Q_ELEMS, out, accum);
    finalize_kernel<<<1, 1, 0, stream>>>(accum, out + Q_ELEMS + N_ROWS);
}

// Round 7
// 412.345 us; speedup vs baseline: 2.4447x; 1.0901x over previous
//
#include <hip/hip_runtime.h>

#define K_CB   8192
#define D_DIM  256
#define N_ROWS 32768
#define Q_ELEMS (N_ROWS * D_DIM)

#define M_FLAG 1.3e-4f   // np-window 6.1e-5 + bf16 score noise + 13-bit pack; passed R4-R6 with absmax 0
#define M_CAND 1.3e-4f
#define CAP    16

typedef __bf16 bf16x8 __attribute__((ext_vector_type(8)));
typedef float  f32x16 __attribute__((ext_vector_type(16)));

// async 16B global->LDS DMA: LDS dest is WAVE-UNIFORM base; HW adds lane*16.
#define ASYNC_COPY16(gp, lp)                                              \
    __builtin_amdgcn_global_load_lds(                                     \
        (const __attribute__((address_space(1))) unsigned int*)(gp),      \
        (__attribute__((address_space(3))) unsigned int*)(lp), 16, 0, 0)

// ws layout (bytes):
//   0        Wsq        [8192 f32]
//   32768    Xsq        [32768 f32]
//   163840   Rmin       [32768 f32]  (packed b1: low 13 mantissa bits = k)
//   294912   accum f32 | 294916 flag_count u32 | 294920 hard_count u32  (memset 12B)
//   294924   flags      [32768 i32]   rows needing np-exact rescore
//   425996   hard_flags [32768 i32]   rows needing full re-sweep (rare)
//   557068   candcnt    [32768 i32]
//   688140   cands      [32768*16 i32]
//   2785296  Wbf        [8192*256 ushort] = bf16(-2w), PRE-SWIZZLED tile layout:
//            byte(k,s) = (k>>7)*65536 + (k&127)*512 + ((s ^ ((k&127)&7))*16)

__device__ inline ushort f2bf(float f) {          // RNE float->bf16
    unsigned u = __float_as_uint(f);
    unsigned r = u + 0x7FFFu + ((u >> 16) & 1u);
    return (ushort)(r >> 16);
}

__device__ inline uint4 pack8(float4 a, float4 b) {
    uint4 o;
    o.x = (unsigned)f2bf(a.x) | ((unsigned)f2bf(a.y) << 16);
    o.y = (unsigned)f2bf(a.z) | ((unsigned)f2bf(a.w) << 16);
    o.z = (unsigned)f2bf(b.x) | ((unsigned)f2bf(b.y) << 16);
    o.w = (unsigned)f2bf(b.z) | ((unsigned)f2bf(b.w) << 16);
    return o;
}

// fused: np-exact w_sq (fp64 sum -> fp32) + Wbf = bf16(-2w), pre-swizzled
__global__ void wsq_wbf_kernel(const float* __restrict__ w, float* __restrict__ wsq,
                               ushort* __restrict__ wbf) {
    int wave = threadIdx.x >> 6, lane = threadIdx.x & 63;
    int row = blockIdx.x * 4 + wave;                 // codeword k
    float4 v = reinterpret_cast<const float4*>(w)[(size_t)row * 64 + lane];
    uint2 o;
    o.x = (unsigned)f2bf(-2.0f * v.x) | ((unsigned)f2bf(-2.0f * v.y) << 16);
    o.y = (unsigned)f2bf(-2.0f * v.z) | ((unsigned)f2bf(-2.0f * v.w) << 16);
    int c = row & 127, tile = row >> 7;
    int s = lane >> 1, hq = lane & 1;
    size_t dst = (size_t)tile * 65536 + (size_t)c * 512 + (size_t)((s ^ (c & 7)) * 16) + hq * 8;
    *reinterpret_cast<uint2*>((char*)wbf + dst) = o;
    double sq = (double)v.x * v.x + (double)v.y * v.y + (double)v.z * v.z + (double)v.w * v.w;
    #pragma unroll
    for (int off = 32; off > 0; off >>= 1) sq += __shfl_down(sq, off, 64);
    if (lane == 0) wsq[row] = (float)sq;
}

__global__ void sqx_kernel(const float* __restrict__ m, float* __restrict__ out) {
    int wave = threadIdx.x >> 6, lane = threadIdx.x & 63;
    int row = blockIdx.x * 4 + wave;
    float4 v = reinterpret_cast<const float4*>(m)[(size_t)row * 64 + lane];
    double s = (double)v.x * v.x + (double)v.y * v.y + (double)v.z * v.z + (double)v.w * v.w;
    #pragma unroll
    for (int off = 32; off > 0; off >>= 1) s += __shfl_down(s, off, 64);
    if (lane == 0) out[row] = (float)s;
}

// Pass 1: A-in-regs 32x32x16 MFMA argmin + inline candidate extraction.
__global__ __launch_bounds__(256, 2) void pass1_kernel(
        const float* __restrict__ x, const ushort* __restrict__ wbf,
        const float* __restrict__ wsq, float* __restrict__ idx_out,
        float* __restrict__ rowmin, int* __restrict__ flags,
        unsigned* __restrict__ flag_count, int* __restrict__ hard_flags,
        unsigned* __restrict__ hard_count, int* __restrict__ candcnt,
        int* __restrict__ cands) {
    __shared__ __align__(16) ushort wt[128 * 256];   // 64 KB swizzled W tile

    const int t = threadIdx.x;
    const int lane = t & 63, ln31 = lane & 31, h = lane >> 5;
    const int wv = t >> 6, rs = wv & 1, cs = wv >> 1;
    const int r0 = blockIdx.x * 64;

    // A fragments (this wave's 32 rows) -> registers
    const int arow = r0 + rs * 32 + ln31;
    const float4* xr = reinterpret_cast<const float4*>(x) + (size_t)arow * 64;
    bf16x8 afr[16];
    #pragma unroll
    for (int kk = 0; kk < 16; ++kk)
        afr[kk] = __builtin_bit_cast(bf16x8, pack8(xr[kk * 4 + h * 2], xr[kk * 4 + h * 2 + 1]));

    float b1[16], b2[16];
    #pragma unroll
    for (int r = 0; r < 16; ++r) { b1[r] = 3.4e38f; b2[r] = 3.4e38f; }

    const int col0 = cs * 64 + ln31, c70 = col0 & 7;
    const char* gW = (const char*)wbf + (size_t)wv * 16384 + (size_t)lane * 16;
    char* lW = (char*)wt + wv * 16384;

    for (int tile = 0; tile < 64; ++tile) {
        __syncthreads();                              // previous tile fully consumed
        const char* gt = gW + (size_t)tile * 65536;
        #pragma unroll
        for (int i = 0; i < 16; ++i)
            ASYNC_COPY16(gt + i * 1024, lW + i * 1024);
        __syncthreads();                              // drains vmcnt before reads

        int kb = tile * 128 + col0;
        float wsk0 = wsq[kb], wsk1 = wsq[kb + 32];

        f32x16 acc0 = {0,0,0,0,0,0,0,0,0,0,0,0,0,0,0,0};
        f32x16 acc1 = {0,0,0,0,0,0,0,0,0,0,0,0,0,0,0,0};
        #pragma unroll
        for (int kk = 0; kk < 16; ++kk) {
            int s = kk * 2 + h;
            bf16x8 bf0 = *reinterpret_cast<const bf16x8*>(&wt[col0 * 256 + ((s ^ c70) * 8)]);
            bf16x8 bf1 = *reinterpret_cast<const bf16x8*>(&wt[(col0 + 32) * 256 + ((s ^ c70) * 8)]);
            acc0 = __builtin_amdgcn_mfma_f32_32x32x16_bf16(afr[kk], bf0, acc0, 0, 0, 0);
            acc1 = __builtin_amdgcn_mfma_f32_32x32x16_bf16(afr[kk], bf1, acc1, 0, 0, 0);
        }

        #pragma unroll
        for (int r = 0; r < 16; ++r) {
            float s0 = acc0[r] + wsk0;
            float p0 = __uint_as_float((__float_as_uint(s0) & 0xFFFFE000u) | (unsigned)kb);
            b2[r] = __builtin_amdgcn_fmed3f(p0, b1[r], b2[r]);
            b1[r] = fminf(p0, b1[r]);
            float s1 = acc1[r] + wsk1;
            float p1 = __uint_as_float((__float_as_uint(s1) & 0xFFFFE000u) | (unsigned)(kb + 32));
            b2[r] = __builtin_amdgcn_fmed3f(p1, b1[r], b2[r]);
            b1[r] = fminf(p1, b1[r]);
        }
    }

    // per-row slot arrays in LDS (stride 65 -> conflict-free columns scans)
    __syncthreads();
    float* sb1 = reinterpret_cast<float*>(wt);        // [64][65]
    float* sb2 = sb1 + 4160;                          // [64][65]
    #pragma unroll
    for (int r = 0; r < 16; ++r) {
        int rl = rs * 32 + (r & 3) + 8 * (r >> 2) + 4 * h;   // C/D row mapping (verified R5/R6)
        sb1[rl * 65 + cs * 32 + ln31] = b1[r];
        sb2[rl * 65 + cs * 32 + ln31] = b2[r];
    }
    __syncthreads();
    if (t < 64) {
        float B1 = 3.4e38f, B2 = 3.4e38f;
        for (int c = 0; c < 64; ++c) {
            float a1 = sb1[t * 65 + c], a2 = sb2[t * 65 + c];
            float nb2 = fminf(fmaxf(B1, a1), fminf(B2, a2));  // 2nd-smallest of {B1,B2,a1,a2}
            B1 = fminf(B1, a1);
            B2 = nb2;
        }
        int row = r0 + t;
        idx_out[row] = (float)(__float_as_uint(B1) & 0x1FFFu);
        rowmin[row]  = B1;
        int nc = 0;
        if (B2 - B1 <= M_FLAG) {
            unsigned pos = atomicAdd(flag_count, 1u);
            if (pos < N_ROWS) flags[pos] = row;
            // candidate extraction from slot best/2nd-best.
            // Lemma: dropped scores in slot L >= final b2(L). If b2(L) > T for all L,
            // {b1(L) <= T} is the complete candidate set; else row is "hard".
            float T = B1 + M_CAND;
            bool hard = false;
            for (int c = 0; c < 64; ++c) {
                float a1 = sb1[t * 65 + c];
                if (a1 <= T) {
                    if (nc < CAP) cands[row * CAP + nc] = (int)(__float_as_uint(a1) & 0x1FFFu);
                    ++nc;
                }
                if (sb2[t * 65 + c] <= T) hard = true;
            }
            if (nc > CAP) hard = true;
            if (hard) {
                nc = 0;                               // full sweep will refill
                unsigned hp = atomicAdd(hard_count, 1u);
                if (hp < N_ROWS) hard_flags[hp] = row;
            }
        }
        candcnt[row] = nc;
    }
}

// Full re-sweep for the rare "hard" rows (same MFMA math as pass1, k-split 8).
__global__ __launch_bounds__(256, 2) void fixup_kernel(
        const float* __restrict__ x, const ushort* __restrict__ wbf,
        const float* __restrict__ wsq, const float* __restrict__ rowmin,
        const int* __restrict__ hard_flags, const unsigned* __restrict__ hard_count,
        int* __restrict__ candcnt, int* __restrict__ cands) {
    __shared__ __align__(16) ushort wt[128 * 256];
    __shared__ int   sh_rows[64];
    __shared__ float sh_thr[64];

    const int t = threadIdx.x;
    const int lane = t & 63, ln31 = lane & 31, h = lane >> 5;
    const int wv = t >> 6, rs = wv & 1, cs = wv >> 1;

    unsigned cu = hard_count[0];
    int cnt = cu > N_ROWS ? N_ROWS : (int)cu;
    int nunits = ((cnt + 63) >> 6) * 8;

    for (int u = blockIdx.x; u < nunits; u += 512) {
        int ksp  = u & 7;
        int base = (u >> 3) * 64;
        int nrows = cnt - base; if (nrows > 64) nrows = 64;

        __syncthreads();
        if (t < 64) {
            int valid = (t < nrows);
            int gr = hard_flags[base + (valid ? t : 0)];
            sh_rows[t] = gr;
            sh_thr[t]  = valid ? rowmin[gr] + M_CAND : -3.4e38f;
        }
        __syncthreads();

        int arow = sh_rows[rs * 32 + ln31];
        const float4* xr = reinterpret_cast<const float4*>(x) + (size_t)arow * 64;
        bf16x8 afr[16];
        #pragma unroll
        for (int kk = 0; kk < 16; ++kk)
            afr[kk] = __builtin_bit_cast(bf16x8, pack8(xr[kk * 4 + h * 2], xr[kk * 4 + h * 2 + 1]));
        float thr_r[16];
        int   rl_r[16];
        #pragma unroll
        for (int r = 0; r < 16; ++r) {
            rl_r[r]  = rs * 32 + (r & 3) + 8 * (r >> 2) + 4 * h;
            thr_r[r] = sh_thr[rl_r[r]];
        }

        const int col0 = cs * 64 + ln31, c70 = col0 & 7;
        char* lW = (char*)wt + wv * 16384;

        for (int tile = 0; tile < 8; ++tile) {
            int ct0 = ksp * 1024 + tile * 128;
            __syncthreads();
            const char* gt = (const char*)wbf + ((size_t)ct0 << 9)
                           + (size_t)wv * 16384 + (size_t)lane * 16;
            #pragma unroll
            for (int i = 0; i < 16; ++i)
                ASYNC_COPY16(gt + i * 1024, lW + i * 1024);
            __syncthreads();

            float wsk0 = wsq[ct0 + col0], wsk1 = wsq[ct0 + col0 + 32];
            f32x16 acc0 = {0,0,0,0,0,0,0,0,0,0,0,0,0,0,0,0};
            f32x16 acc1 = {0,0,0,0,0,0,0,0,0,0,0,0,0,0,0,0};
            #pragma unroll
            for (int kk = 0; kk < 16; ++kk) {
                int s = kk * 2 + h;
                bf16x8 bf0 = *reinterpret_cast<const bf16x8*>(&wt[col0 * 256 + ((s ^ c70) * 8)]);
                bf16x8 bf1 = *reinterpret_cast<const bf16x8*>(&wt[(col0 + 32) * 256 + ((s ^ c70) * 8)]);
                acc0 = __builtin_amdgcn_mfma_f32_32x32x16_bf16(afr[kk], bf0, acc0, 0, 0, 0);
                acc1 = __builtin_amdgcn_mfma_f32_32x32x16_bf16(afr[kk], bf1, acc1, 0, 0, 0);
            }
            #pragma unroll
            for (int r = 0; r < 16; ++r) {
                float s0 = acc0[r] + wsk0;
                if (s0 <= thr_r[r]) {
                    int grow = sh_rows[rl_r[r]];
                    int pos = atomicAdd(&candcnt[grow], 1);
                    if (pos < CAP) cands[grow * CAP + pos] = ct0 + col0;
                }
                float s1 = acc1[r] + wsk1;
                if (s1 <= thr_r[r]) {
                    int grow = sh_rows[rl_r[r]];
                    int pos = atomicAdd(&candcnt[grow], 1);
                    if (pos < CAP) cands[grow * CAP + pos] = ct0 + col0 + 32;
                }
            }
        }
    }
}

// np-exact rescore (verified R3): q = fl32(fl32(Xsq - 2*fl32(dot64)) + Wsq), lowest-index ties
__global__ __launch_bounds__(256) void rescore_kernel(
        const float* __restrict__ x, const float* __restrict__ w,
        const float* __restrict__ wsq, const float* __restrict__ xsq,
        const int* __restrict__ flags, const unsigned* __restrict__ flag_count,
        const int* __restrict__ candcnt, const int* __restrict__ cands,
        float* __restrict__ idx_out) {
    int wid  = (blockIdx.x * 256 + threadIdx.x) >> 6;
    int lane = threadIdx.x & 63;
    unsigned cu = flag_count[0];
    int cnt = (cu > N_ROWS) ? N_ROWS : (int)cu;

    for (int fi = wid; fi < cnt; fi += 1024) {
        int row = flags[fi];
        float4 xv = reinterpret_cast<const float4*>(x)[(size_t)row * 64 + lane];
        float Xs = xsq[row];
        int nc = candcnt[row]; if (nc > CAP) nc = CAP;
        float bq = 3.4e38f; int bk = -1;
        for (int c = 0; c < nc; ++c) {
            int k = cands[row * CAP + c];
            float4 wv = reinterpret_cast<const float4*>(w)[(size_t)k * 64 + lane];
            double d = (double)xv.x * wv.x + (double)xv.y * wv.y
                     + (double)xv.z * wv.z + (double)xv.w * wv.w;
            #pragma unroll
            for (int off = 1; off < 64; off <<= 1) d += __shfl_xor(d, off, 64);
            float XW = (float)d;
            float t3 = fmaf(-2.0f, XW, Xs);
            float qv = t3 + wsq[k];
            if (qv < bq || (qv == bq && k < bk) || bk < 0) { bq = qv; bk = k; }
        }
        if (lane == 0 && bk >= 0) idx_out[row] = (float)bk;
    }
}

__global__ __launch_bounds__(256) void gather_loss_kernel(
        const float* __restrict__ x, const float* __restrict__ w,
        const float* __restrict__ idx_f, float* __restrict__ out_q,
        float* __restrict__ accum) {
    const int nf4 = Q_ELEMS / 4;
    float lsum = 0.0f;
    for (int e = blockIdx.x * blockDim.x + threadIdx.x; e < nf4;
         e += gridDim.x * blockDim.x) {
        int row = e >> 6, d4 = e & 63;
        int k = (int)idx_f[row];
        float4 xv = reinterpret_cast<const float4*>(x)[e];
        float4 qv = reinterpret_cast<const float4*>(w)[(size_t)k * 64 + d4];
        float4 ov;
        ov.x = xv.x + (qv.x - xv.x);
        ov.y = xv.y + (qv.y - xv.y);
        ov.z = xv.z + (qv.z - xv.z);
        ov.w = xv.w + (qv.w - xv.w);
        reinterpret_cast<float4*>(out_q)[e] = ov;
        float dx = xv.x - qv.x, dy = xv.y - qv.y, dz = xv.z - qv.z, dw = xv.w - qv.w;
        lsum += dx * dx + dy * dy + dz * dz + dw * dw;
    }
    #pragma unroll
    for (int off = 32; off > 0; off >>= 1) lsum += __shfl_down(lsum, off, 64);
    __shared__ float ssum[4];
    if ((threadIdx.x & 63) == 0) ssum[threadIdx.x >> 6] = lsum;
    __syncthreads();
    if (threadIdx.x == 0)
        atomicAdd(accum, ssum[0] + ssum[1] + ssum[2] + ssum[3]);
}

__global__ void finalize_kernel(const float* __restrict__ accum,
                                float* __restrict__ out_tail) {
    float mse = accum[0] / (float)Q_ELEMS;
    float commit = 0.25f * mse;
    out_tail[0] = commit;
    out_tail[1] = mse;
    out_tail[2] = commit + mse;
}

extern "C" void kernel_launch(void* const* d_in, const int* in_sizes, int n_in,
                              void* d_out, int out_size, void* d_ws, size_t ws_size,
                              hipStream_t stream) {
    const float* x = (const float*)d_in[0];
    const float* w = (const float*)d_in[1];
    float* out = (float*)d_out;

    char* ws = (char*)d_ws;
    float*    Wsq        = (float*)ws;
    float*    Xsq        = (float*)(ws + 32768);
    float*    Rmin       = (float*)(ws + 163840);
    float*    accum      = (float*)(ws + 294912);
    unsigned* flag_count = (unsigned*)(ws + 294916);
    unsigned* hard_count = (unsigned*)(ws + 294920);
    int*      flags      = (int*)(ws + 294924);
    int*      hard_flags = (int*)(ws + 425996);
    int*      candcnt    = (int*)(ws + 557068);
    int*      cands      = (int*)(ws + 688140);
    ushort*   Wbf        = (ushort*)(ws + 2785296);

    hipMemsetAsync(ws + 294912, 0, 12, stream);   // accum + flag_count + hard_count
    wsq_wbf_kernel<<<K_CB / 4, 256, 0, stream>>>(w, Wsq, Wbf);
    sqx_kernel<<<N_ROWS / 4, 256, 0, stream>>>(x, Xsq);
    pass1_kernel<<<N_ROWS / 64, 256, 0, stream>>>(x, Wbf, Wsq, out + Q_ELEMS,
                                                  Rmin, flags, flag_count,
                                                  hard_flags, hard_count,
                                                  candcnt, cands);
    fixup_kernel<<<512, 256, 0, stream>>>(x, Wbf, Wsq, Rmin, hard_flags, hard_count,
                                          candcnt, cands);
    rescore_kernel<<<256, 256, 0, stream>>>(x, w, Wsq, Xsq, flags, flag_count,
                                            candcnt, cands, out + Q_ELEMS);
    gather_loss_kernel<<<8192, 256, 0, stream>>>(x, w, out + Q_ELEMS, out, accum);
    finalize_kernel<<<1, 1, 0, stream>>>(accum, out + Q_ELEMS + N_ROWS);
}